// Round 7
// baseline (1034.052 us; speedup 1.0000x reference)
//
#include <hip/hip_runtime.h>
#include <math.h>

#define B_    8
#define L_    2000
#define V_    50000
#define E_    300
#define NL_   8922
#define NLP_  8960   // padded label count (multiple of 64)
#define LW_   10
#define F_    200
#define KW_   10
#define H_    200
#define FEAT_ 500
#define LP_   1991   // L - K + 1

typedef __attribute__((ext_vector_type(8))) short bf16x8;
typedef __attribute__((ext_vector_type(4))) float f32x4;

static __device__ __forceinline__ unsigned short f2b(float f) {
  unsigned u = __builtin_bit_cast(unsigned, f);
  u += 0x7FFF + ((u >> 16) & 1);   // round-to-nearest-even
  return (unsigned short)(u >> 16);
}
static __device__ __forceinline__ float b2f(unsigned short u) {
  unsigned v = ((unsigned)u) << 16;
  return __builtin_bit_cast(float, v);
}
static __device__ __forceinline__ float fast_tanh(float x) {
  x = fminf(fmaxf(x, -10.f), 10.f);
  float t = __expf(2.f * x);
  return (t - 1.f) / (t + 1.f);
}
// async global->LDS DMA, 16B/lane, zero result VGPRs.
static __device__ __forceinline__ void stage16(const void* g, void* l) {
  __builtin_amdgcn_global_load_lds(
      (const __attribute__((address_space(1))) unsigned int*)g,
      (__attribute__((address_space(3))) unsigned int*)l, 16, 0, 0);
}

#define MFMA(a, b, c) __builtin_amdgcn_mfma_f32_16x16x32_bf16(a, b, c, 0, 0, 0)

// Fragment conventions (mfma_f32_16x16x32_bf16, m89/m91-verified):
//   A[m][k]: m = lane&15, k = (lane>>4)*8 + j
//   B[n][k]: n = lane&15, k = (lane>>4)*8 + j
//   D[m][n]: m-row = (lane>>4)*4 + reg, n-col = lane&15
// Frag-major: tile*512 shorts + lane*8 + j -> 1 KB contiguous per frag.

// ---------------------------------------------------------------------------
// avg fp32 [n][300] (k_agg input), avgb bf16 [n][320], geF feats 0..299
__global__ __launch_bounds__(256) void k_avg(const float* __restrict__ we,
                                             const int* __restrict__ lidx,
                                             const float* __restrict__ lmask,
                                             float* __restrict__ avg,
                                             unsigned short* __restrict__ avgb,
                                             unsigned short* __restrict__ geF) {
  int idx = blockIdx.x * 256 + threadIdx.x;
  if (idx >= NLP_ * 80) return;
  int n = idx / 80, e4 = idx - n * 80;
  if (n >= NL_ || e4 >= 75) {
    *(ushort4*)&avgb[(size_t)n * 320 + e4 * 4] = make_ushort4(0, 0, 0, 0);
    return;
  }
  float ax = 0.f, ay = 0.f, az = 0.f, aw = 0.f, ms = 0.f;
#pragma unroll
  for (int w = 0; w < LW_; ++w) {
    float mw = lmask[n * LW_ + w];
    const float4 f = *(const float4*)&we[(size_t)lidx[n * LW_ + w] * E_ + e4 * 4];
    ax = fmaf(f.x, mw, ax); ay = fmaf(f.y, mw, ay);
    az = fmaf(f.z, mw, az); aw = fmaf(f.w, mw, aw);
    ms += mw;
  }
  float inv = 1.f / ms;
  float4 v = {ax * inv, ay * inv, az * inv, aw * inv};
  *(float4*)&avg[(size_t)n * 300 + e4 * 4] = v;
  *(ushort4*)&avgb[(size_t)n * 320 + e4 * 4] =
      make_ushort4(f2b(v.x), f2b(v.y), f2b(v.z), f2b(v.w));
  int ntg = n >> 4, quad = (n >> 2) & 3, r = n & 3;
  int ftg = (e4 * 4) >> 4, c0 = (e4 * 4) & 15;
  size_t tb = (((size_t)ntg * 32 + ftg) << 8);
  float vv[4] = {v.x, v.y, v.z, v.w};
#pragma unroll
  for (int t = 0; t < 4; ++t)
    geF[(tb + quad * 16 + c0 + t) * 4 + r] = f2b(vv[t]);
}

// ---------------------------------------------------------------------------
// agg[n] sparse scan -> aggF bf16 A-frag-major [mtile(560)][ks(10)][512]
__global__ __launch_bounds__(256) void k_agg(const float* __restrict__ adj,
                                             const float* __restrict__ avg,
                                             const float* __restrict__ nnb,
                                             unsigned short* __restrict__ aggF) {
  __shared__ int s_idx[1024];
  __shared__ float s_val[1024];
  __shared__ float s_agg[320];
  __shared__ int s_cnt;
  const int n = blockIdx.x;
  const int tid = threadIdx.x;
  if (tid == 0) s_cnt = 0;
  __syncthreads();
  const float* row = adj + (size_t)n * NL_;
  for (int j = tid; j < NL_; j += 256) {
    float v = row[j];
    if (v != 0.f) {
      int p = atomicAdd(&s_cnt, 1);
      if (p < 1024) { s_idx[p] = j; s_val[p] = v; }
    }
  }
  __syncthreads();
  const int m = min(s_cnt, 1024);
  const float inv = 1.f / nnb[n];
  float a0 = 0.f, a1 = 0.f;
  for (int i = 0; i < m; ++i) {
    const float* ar = avg + (size_t)s_idx[i] * 300;
    float v = s_val[i];
    a0 = fmaf(v, ar[tid], a0);
    if (tid < E_ - 256) a1 = fmaf(v, ar[tid + 256], a1);
  }
  s_agg[tid] = a0 * inv;
  if (tid < E_ - 256) s_agg[tid + 256] = a1 * inv;
  if (tid >= 44 && tid < 64) s_agg[tid + 256] = 0.f;  // zero e 300..319
  __syncthreads();
  if (tid < 320) {
    int e = tid;
    int ks = e >> 5, qA = (e >> 3) & 3, jj = e & 7;
    aggF[(((size_t)((n >> 4) * 10 + ks)) << 9) + ((qA << 4) + (n & 15)) * 8 + jj] =
        f2b(s_agg[e]);
  }
}

// ---------------------------------------------------------------------------
// gh via MFMA: geF[n][300..499] = relu(aggF @ WgF + bg). 140 blocks x 64 labels.
__global__ __launch_bounds__(256) void k_gh2(const unsigned short* __restrict__ aggF,
                                             const unsigned short* __restrict__ WgF,
                                             const float* __restrict__ bg,
                                             unsigned short* __restrict__ geF) {
  const int n0g = blockIdx.x * 64;
  const int tid = threadIdx.x;
  const int wv = tid >> 6, lane = tid & 63, quad = lane >> 4, c16 = lane & 15;
  const int mt = wv;
  f32x4 acc[14];
#pragma unroll
  for (int nt = 0; nt < 14; ++nt) acc[nt] = (f32x4){0.f, 0.f, 0.f, 0.f};
#pragma unroll
  for (int ks = 0; ks < 10; ++ks) {
    bf16x8 a = *(const bf16x8*)
        &aggF[(((size_t)(((n0g >> 4) + mt) * 10 + ks)) << 9) + (lane << 3)];
#pragma unroll
    for (int nt = 0; nt < 14; ++nt) {
      bf16x8 bw = *(const bf16x8*)&WgF[(((size_t)(nt * 10 + ks)) << 9) + (lane << 3)];
      acc[nt] = MFMA(a, bw, acc[nt]);
    }
  }
#pragma unroll
  for (int nt = 0; nt < 14; ++nt) {
    int h = nt * 16 + c16;
    if (h < H_) {
      float bgv = bg[h];
      int feat = 300 + h;
      int ftg = feat >> 4, cg = feat & 15;
#pragma unroll
      for (int r = 0; r < 4; ++r) {
        int n = n0g + mt * 16 + quad * 4 + r;
        if (n < NL_)
          geF[((((size_t)(n >> 4) * 32 + ftg) << 8) + (quad << 4) + cg) * 4 + r] =
              f2b(fmaxf(acc[nt][r] + bgv, 0.f));
      }
    }
  }
}

// ---------------------------------------------------------------------------
// Fused weight-layout prep: WcF, WpF, WoF, WgF (frag-major, zero-padded)
__global__ __launch_bounds__(256) void k_wprep(const float* __restrict__ Wc,
                                               const float* __restrict__ Wp,
                                               const float* __restrict__ Wo,
                                               const float* __restrict__ Wg,
                                               unsigned short* __restrict__ WcF,
                                               unsigned short* __restrict__ WpF,
                                               unsigned short* __restrict__ WoF,
                                               unsigned short* __restrict__ WgF) {
  int idx = blockIdx.x * 256 + threadIdx.x;
  if (idx < 819200) {  // WcF [koff(10)][ft(16)][ks(10)][512]
    int koff = idx / (16 * 10 * 512);
    int rem = idx - koff * (16 * 10 * 512);
    int ft = rem / (10 * 512);
    int rem2 = rem - ft * (10 * 512);
    int ks = rem2 >> 9, t = rem2 & 511;
    int lane = t >> 3, j = t & 7;
    int f = ft * 16 + (lane & 15);
    int e = ks * 32 + (lane >> 4) * 8 + j;
    float v = (f < F_ && e < E_) ? Wc[((size_t)f * E_ + e) * KW_ + koff] : 0.f;
    WcF[idx] = f2b(v);
    return;
  }
  idx -= 819200;
  if (idx < 71680) {   // WpF [et(20)][kt(7)][512]
    int et = idx / (7 * 512);
    int rem = idx - et * (7 * 512);
    int kt = rem >> 9, t = rem & 511;
    int lane = t >> 3, j = t & 7;
    int e = et * 16 + (lane & 15);
    int f = kt * 32 + (lane >> 4) * 8 + j;
    float v = (e < E_ && f < F_) ? Wp[(size_t)f * E_ + e] : 0.f;
    WpF[idx] = f2b(v);
    return;
  }
  idx -= 71680;
  if (idx < 114688) {  // WoF [g(32)][kt(7)][512]
    int g = idx / (7 * 512);
    int rem = idx - g * (7 * 512);
    int kt = rem >> 9, t = rem & 511;
    int lane = t >> 3, j = t & 7;
    int feat = g * 16 + (lane & 15);
    int f = kt * 32 + (lane >> 4) * 8 + j;
    float v = (feat < FEAT_ && f < F_) ? Wo[(size_t)f * FEAT_ + feat] : 0.f;
    WoF[idx] = f2b(v);
    return;
  }
  idx -= 114688;
  if (idx < 71680) {   // WgF [nt(14)][ks(10)][512]
    int nt = idx / (10 * 512);
    int rem = idx - nt * (10 * 512);
    int ks = rem >> 9, t = rem & 511;
    int lane = t >> 3, j = t & 7;
    int h = nt * 16 + (lane & 15);
    int e = ks * 32 + (lane >> 4) * 8 + j;
    float v = (h < H_ && e < E_) ? Wg[(size_t)e * H_ + h] : 0.f;
    WgF[idx] = f2b(v);
  }
}

// ---------------------------------------------------------------------------
// Fused conv + pj -> cF [b][ft2(16)][su(64)][512], pjF [b][lt(128)][ks(10)][512]
__global__ __launch_bounds__(256) void k_cpj(const int* __restrict__ x,
                                             const float* __restrict__ mask,
                                             const float* __restrict__ we,
                                             const unsigned short* __restrict__ WcF,
                                             const float* __restrict__ bc,
                                             const unsigned short* __restrict__ WpF,
                                             const float* __restrict__ bp,
                                             unsigned short* __restrict__ cF,
                                             unsigned short* __restrict__ pjF) {
  __shared__ __attribute__((aligned(16))) unsigned char smem[78896];
  unsigned short* s_xe  = (unsigned short*)smem;            // [73][344]
  unsigned short* s_pjF = (unsigned short*)smem;            // alias
  unsigned short* s_cA  = (unsigned short*)(smem + 50224);  // [4][7][512]

  const int b = blockIdx.y;
  const int l0 = blockIdx.x * 64;
  const int tid = threadIdx.x;
  const int wv = tid >> 6, lane = tid & 63, quad = lane >> 4, c16 = lane & 15;

  for (int i = tid; i < 73 * 75; i += 256) {
    int row = i / 75, e4 = i - row * 75;
    int l = l0 + row;
    float4 v = {0.f, 0.f, 0.f, 0.f};
    if (l < L_) {
      int bl = b * L_ + l;
      v = *(const float4*)&we[(size_t)x[bl] * E_ + e4 * 4];
      float mm = mask[bl];
      v.x *= mm; v.y *= mm; v.z *= mm; v.w *= mm;
    }
    *(ushort4*)&s_xe[row * 344 + e4 * 4] =
        make_ushort4(f2b(v.x), f2b(v.y), f2b(v.z), f2b(v.w));
  }
  for (int i = tid; i < 73 * 5; i += 256) {
    int row = i / 5, c = i - row * 5;
    *(ushort4*)&s_xe[row * 344 + (75 + c) * 4] = make_ushort4(0, 0, 0, 0);
  }
  __syncthreads();

  f32x4 acc[4][4];
#pragma unroll
  for (int mt = 0; mt < 4; ++mt)
#pragma unroll
    for (int j = 0; j < 4; ++j) acc[mt][j] = (f32x4){0.f, 0.f, 0.f, 0.f};
  for (int koff = 0; koff < KW_; ++koff) {
#pragma unroll
    for (int ks = 0; ks < 10; ++ks) {
      bf16x8 a[4];
#pragma unroll
      for (int mt = 0; mt < 4; ++mt)
        a[mt] = *(const bf16x8*)&s_xe[(mt * 16 + c16 + koff) * 344 + ks * 32 + quad * 8];
#pragma unroll
      for (int jj = 0; jj < 4; ++jj) {
        bf16x8 bw = *(const bf16x8*)
            &WcF[(((size_t)((koff * 16 + wv * 4 + jj) * 10 + ks)) << 9) + (lane << 3)];
#pragma unroll
        for (int mt = 0; mt < 4; ++mt) acc[mt][jj] = MFMA(a[mt], bw, acc[mt][jj]);
      }
    }
  }
  unsigned short* cFb = cF + (size_t)b * (16 * 64 * 512);
#pragma unroll
  for (int jj = 0; jj < 4; ++jj) {
    const int ft2 = wv * 4 + jj;
    const int f = ft2 * 16 + c16;
    const float bcv = (f < F_) ? bc[f] : 0.f;
    const int kt = ft2 >> 1;
    const int qA = ((ft2 & 1) << 1) | (c16 >> 3);
    const int jA = c16 & 7;
#pragma unroll
    for (int mt = 0; mt < 4; ++mt) {
      unsigned short u[4];
#pragma unroll
      for (int r = 0; r < 4; ++r) u[r] = f2b(fmaxf(acc[mt][jj][r] + bcv, 0.f));
      int su = (l0 >> 5) + (mt >> 1);
      int lane_c = ((((mt & 1) << 1) | (quad >> 1)) << 4) + c16;
      *(ushort4*)&cFb[(((size_t)(ft2 * 64 + su)) << 9) + lane_c * 8 + ((quad & 1) << 2)] =
          make_ushort4(u[0], u[1], u[2], u[3]);
      if (ft2 < 14) {
#pragma unroll
        for (int r = 0; r < 4; ++r)
          s_cA[(((size_t)(mt * 7 + kt)) << 9) + ((qA << 4) + quad * 4 + r) * 8 + jA] = u[r];
      }
    }
  }
  __syncthreads();

  f32x4 pacc[4][5];
#pragma unroll
  for (int mt = 0; mt < 4; ++mt)
#pragma unroll
    for (int j = 0; j < 5; ++j) pacc[mt][j] = (f32x4){0.f, 0.f, 0.f, 0.f};
#pragma unroll
  for (int kt = 0; kt < 7; ++kt) {
    bf16x8 a[4];
#pragma unroll
    for (int mt = 0; mt < 4; ++mt)
      a[mt] = *(const bf16x8*)&s_cA[(((size_t)(mt * 7 + kt)) << 9) + (lane << 3)];
#pragma unroll
    for (int j = 0; j < 5; ++j) {
      bf16x8 bw = *(const bf16x8*)
          &WpF[(((size_t)((wv * 5 + j) * 7 + kt)) << 9) + (lane << 3)];
#pragma unroll
      for (int mt = 0; mt < 4; ++mt) pacc[mt][j] = MFMA(a[mt], bw, pacc[mt][j]);
    }
  }
  __syncthreads();
#pragma unroll
  for (int j = 0; j < 5; ++j) {
    const int et = wv * 5 + j;
    const int e = et * 16 + c16;
    const float bpe = (e < E_) ? bp[e] : 0.f;
    const int ks = et >> 1;
    const int qP = ((et & 1) << 1) | (c16 >> 3);
    const int jP = c16 & 7;
#pragma unroll
    for (int mt = 0; mt < 4; ++mt) {
#pragma unroll
      for (int r = 0; r < 4; ++r) {
        float v = (e < E_) ? fast_tanh(pacc[mt][j][r] + bpe) : 0.f;
        s_pjF[(((size_t)(mt * 10 + ks)) << 9) + ((qP << 4) + quad * 4 + r) * 8 + jP] = f2b(v);
      }
    }
  }
  __syncthreads();
  {
    unsigned short* dst = pjF + (((size_t)((b * 128 + (l0 >> 4)) * 10)) << 9);
    for (int i = tid; i < 2560; i += 256)
      *(uint4*)&dst[i * 8] = *(const uint4*)&s_pjF[i * 8];
  }
}

// ---------------------------------------------------------------------------
// Fused attention + proj + logits. 64 labels/block.
// Wave = (l-half lh, label-half nh): 32 labels in regs, 10 pj A-reads/chunk.
__global__ __launch_bounds__(256, 2) void k_attn(
    const unsigned short* __restrict__ pjF,   // [8][128][10][512]
    const unsigned short* __restrict__ cF,    // [8][16][64][512]
    const unsigned short* __restrict__ avgb,  // [8960][320]
    const unsigned short* __restrict__ WoF,   // [32][7][512]
    const unsigned short* __restrict__ geF,   // [560][32][64][4]
    const float* __restrict__ bo,
    float* __restrict__ out) {
  __shared__ __attribute__((aligned(16))) unsigned char smem[74752];
  // buf0 @0 (pj 20480 + cF 14336), buf1 @34816, Ps @69632 (4 KB),
  // s_wsum @73728, s_sum @74240, s_lg @74496. AO aliases buf0 (28672 B).
  unsigned short* Ps  = (unsigned short*)(smem + 69632);
  float* s_wsum = (float*)(smem + 73728);
  float* s_sum  = (float*)(smem + 74240);
  float* s_lg   = (float*)(smem + 74496);
  unsigned short* AOs = (unsigned short*)smem;

  const int tid = threadIdx.x;
  const int b  = blockIdx.x & 7;               // XCD-locality swizzle
  const int n0 = (blockIdx.x >> 3) << 6;
  const int wv = tid >> 6, lane = tid & 63, quad = lane >> 4, c16 = lane & 15;
  const int lh = wv & 1, nh = wv >> 1;

  if (tid < 64) s_lg[tid] = 0.f;

  // 32 labels' avg B-frags in regs (80 VGPRs)
  bf16x8 bavg[10][2];
#pragma unroll
  for (int ks = 0; ks < 10; ++ks)
#pragma unroll
    for (int nt = 0; nt < 2; ++nt)
      bavg[ks][nt] = *(const bf16x8*)
          &avgb[(size_t)(n0 + nh * 32 + nt * 16 + c16) * 320 + ks * 32 + quad * 8];

  const unsigned short* pjb = pjF + (size_t)b * (128 * 10 * 512);
  const unsigned short* cFb = cF + (size_t)b * (16 * 64 * 512);

  // stage chunk 0 into buf0
  {
    const unsigned char* pg = (const unsigned char*)pjb;
#pragma unroll
    for (int t = 0; t < 5; ++t) {
      int off = (wv * 5 + t) << 10;
      stage16(pg + off + lane * 16, smem + off);
    }
#pragma unroll
    for (int t = 0; t < 4; ++t) {
      int ft = wv + t * 4;
      if (ft < 14)
        stage16((const unsigned char*)cFb + (((size_t)(ft * 64)) << 10) + lane * 16,
                smem + 20480 + (ft << 10));
    }
  }

  f32x4 o[2][7];
#pragma unroll
  for (int nt = 0; nt < 2; ++nt)
#pragma unroll
    for (int j = 0; j < 7; ++j) o[nt][j] = (f32x4){0.f, 0.f, 0.f, 0.f};
  float ssum[2] = {0.f, 0.f};

  for (int lc = 0; lc < 64; ++lc) {
    __builtin_amdgcn_s_waitcnt(0);   // buf[lc&1] staged; prior PV reads of Ps done
    __syncthreads();
    unsigned char* cur = smem + ((lc & 1) ? 34816 : 0);
    unsigned char* nxt = smem + ((lc & 1) ? 0 : 34816);
    if (lc + 1 < 64) {
      const unsigned char* pg =
          (const unsigned char*)pjb + (((size_t)((lc + 1) * 20)) << 10);
#pragma unroll
      for (int t = 0; t < 5; ++t) {
        int off = (wv * 5 + t) << 10;
        stage16(pg + off + lane * 16, nxt + off);
      }
#pragma unroll
      for (int t = 0; t < 4; ++t) {
        int ft = wv + t * 4;
        if (ft < 14)
          stage16((const unsigned char*)cFb + (((size_t)(ft * 64 + lc + 1)) << 10) + lane * 16,
                  nxt + 20480 + (ft << 10));
      }
    }
    // ---- scores: A = own l-half pj (LDS, 10 reads), B = 32 labels (regs) ----
    const unsigned short* pt = (const unsigned short*)cur;
    f32x4 acc0 = (f32x4){0.f, 0.f, 0.f, 0.f};
    f32x4 acc1 = (f32x4){0.f, 0.f, 0.f, 0.f};
#pragma unroll
    for (int ks = 0; ks < 10; ++ks) {
      bf16x8 a = *(const bf16x8*)(pt + ((lh * 10 + ks) << 9) + (lane << 3));
      acc0 = MFMA(a, bavg[ks][0], acc0);
      acc1 = MFMA(a, bavg[ks][1], acc1);
    }
    // ---- exp (bounded; no max) -> Ps (A-frag per n-tile), reg sums ----
    const int lb = (lc << 5) + lh * 16 + quad * 4;
#pragma unroll
    for (int nt = 0; nt < 2; ++nt) {
      f32x4 av = nt ? acc1 : acc0;
      float psum = 0.f;
      unsigned short u[4];
#pragma unroll
      for (int r = 0; r < 4; ++r) {
        float p = __expf(av[r]);
        if (lc >= 62 && (lb + r >= LP_)) p = 0.f;
        psum += p;
        u[r] = f2b(p);
      }
      *(ushort4*)&Ps[((nh * 2 + nt) << 9) +
                     ((lh * 2 + (quad >> 1)) * 16 + c16) * 8 + ((quad & 1) << 2)] =
          make_ushort4(u[0], u[1], u[2], u[3]);
      psum += __shfl_xor(psum, 16);
      psum += __shfl_xor(psum, 32);
      ssum[nt] += psum;
    }
    __syncthreads();  // Ps visible (cross-wave l-halves)
    // ---- PV: wave = (n-half nh, f-half lh). 2 A + 7 B reads, 14 MFMA ----
    {
      bf16x8 aP0 = *(const bf16x8*)&Ps[((nh * 2) << 9) + (lane << 3)];
      bf16x8 aP1 = *(const bf16x8*)&Ps[((nh * 2 + 1) << 9) + (lane << 3)];
      const unsigned short* cc = (const unsigned short*)(cur + 20480);
#pragma unroll
      for (int ft = 0; ft < 7; ++ft) {
        bf16x8 bC = *(const bf16x8*)(cc + ((lh * 7 + ft) << 9) + (lane << 3));
        o[0][ft] = MFMA(aP0, bC, o[0][ft]);
        o[1][ft] = MFMA(aP1, bC, o[1][ft]);
      }
    }
  }

  // ---- combine sums across l-half wave pairs ----
  if (lane < 16) {
    s_wsum[wv * 32 + lane] = ssum[0];
    s_wsum[wv * 32 + 16 + lane] = ssum[1];
  }
  __syncthreads();
  if (tid < 64) {
    int g = tid >> 5, idx = tid & 31;
    s_sum[tid] = s_wsum[(g * 2) * 32 + idx] + s_wsum[(g * 2 + 1) * 32 + idx];
  }
  __syncthreads();
  // ---- normalize -> AO (A-frag-major [ntile(4)][kt(7)][512], aliases buf0) ----
#pragma unroll
  for (int nt = 0; nt < 2; ++nt) {
    const int ntile = nh * 2 + nt;
    float inv4[4];
#pragma unroll
    for (int r = 0; r < 4; ++r) inv4[r] = 1.f / s_sum[ntile * 16 + quad * 4 + r];
#pragma unroll
    for (int ft = 0; ft < 7; ++ft) {
      int f = (lh * 7 + ft) * 16 + c16;
      int kt = f >> 5, qA = (f >> 3) & 3, jA = f & 7;
#pragma unroll
      for (int r = 0; r < 4; ++r)
        AOs[((ntile * 7 + kt) << 9) + ((qA << 4) + quad * 4 + r) * 8 + jA] =
            f2b(o[nt][ft][r] * inv4[r]);
    }
  }
  __syncthreads();
  // ---- proj: waves split feat (8 tiles each); relu + dot geF -> logits ----
  float la[4][4];
#pragma unroll
  for (int nt = 0; nt < 4; ++nt)
#pragma unroll
    for (int r = 0; r < 4; ++r) la[nt][r] = 0.f;
#pragma unroll
  for (int i = 0; i < 8; ++i) {
    const int ftg = wv * 8 + i;
    const int feat = (ftg << 4) + c16;
    f32x4 pa[4];
#pragma unroll
    for (int nt = 0; nt < 4; ++nt) pa[nt] = (f32x4){0.f, 0.f, 0.f, 0.f};
    const unsigned short* wof = WoF + (((size_t)(ftg * 7)) << 9) + (lane << 3);
#pragma unroll
    for (int kt = 0; kt < 7; ++kt) {
      bf16x8 bw = *(const bf16x8*)(wof + (kt << 9));
#pragma unroll
      for (int nt = 0; nt < 4; ++nt) {
        bf16x8 aa = *(const bf16x8*)&AOs[((nt * 7 + kt) << 9) + (lane << 3)];
        pa[nt] = MFMA(aa, bw, pa[nt]);
      }
    }
    const float bof = (feat < FEAT_) ? bo[feat] : 0.f;
#pragma unroll
    for (int nt = 0; nt < 4; ++nt) {
      ushort4 g4 = *(const ushort4*)
          &geF[((((size_t)(n0 >> 4) + nt) * 32 + ftg) << 8) + (lane << 2)];
      float gv[4] = {b2f(g4.x), b2f(g4.y), b2f(g4.z), b2f(g4.w)};
#pragma unroll
      for (int r = 0; r < 4; ++r) {
        float pv = fmaxf(pa[nt][r] + bof, 0.f);
        la[nt][r] = fmaf(pv, gv[r], la[nt][r]);
      }
    }
  }
#pragma unroll
  for (int nt = 0; nt < 4; ++nt)
#pragma unroll
    for (int r = 0; r < 4; ++r) {
      float v = la[nt][r];
      v += __shfl_xor(v, 1); v += __shfl_xor(v, 2);
      v += __shfl_xor(v, 4); v += __shfl_xor(v, 8);
      if (c16 == 0) atomicAdd(&s_lg[nt * 16 + quad * 4 + r], v);
    }
  __syncthreads();
  if (tid < 64) {
    int ng = n0 + tid;
    if (ng < NL_) out[(size_t)b * NL_ + ng] = s_lg[tid];
  }
}

// ---------------------------------------------------------------------------
__global__ __launch_bounds__(1024) void k_loss(const float* __restrict__ lgts,
                                               const float* __restrict__ y,
                                               float* __restrict__ loss) {
  __shared__ float red[1024];
  const int tid = threadIdx.x;
  float s = 0.f;
  for (int i = tid; i < B_ * NL_; i += 1024) {
    float l = lgts[i], yy = y[i];
    s += fmaxf(l, 0.f) - l * yy + log1pf(expf(-fabsf(l)));
  }
  red[tid] = s;
  __syncthreads();
  for (int st = 512; st > 0; st >>= 1) {
    if (tid < st) red[tid] += red[tid + st];
    __syncthreads();
  }
  if (tid == 0) loss[0] = red[0] * (1.f / B_);
}

// ---------------------------------------------------------------------------
extern "C" void kernel_launch(void* const* d_in, const int* in_sizes, int n_in,
                              void* d_out, int out_size, void* d_ws, size_t ws_size,
                              hipStream_t stream) {
  const int*   x     = (const int*)  d_in[0];
  const float* y     = (const float*)d_in[1];
  const float* mask  = (const float*)d_in[2];
  const float* we    = (const float*)d_in[3];
  const int*   lidx  = (const int*)  d_in[4];
  const float* lmask = (const float*)d_in[5];
  const float* adj   = (const float*)d_in[6];
  const float* nnb   = (const float*)d_in[7];
  const float* Wg    = (const float*)d_in[8];
  const float* bg    = (const float*)d_in[9];
  const float* Wc    = (const float*)d_in[10];
  const float* bc    = (const float*)d_in[11];
  const float* Wp    = (const float*)d_in[12];
  const float* bp    = (const float*)d_in[13];
  const float* Wo    = (const float*)d_in[14];
  const float* bo    = (const float*)d_in[15];
  float* out = (float*)d_out;
  char* W = (char*)d_ws;

  unsigned short* pjF  = (unsigned short*)(W + 0);          // 10,485,760
  unsigned short* cF   = (unsigned short*)(W + 10485760);   //  8,388,608
  unsigned short* avgb = (unsigned short*)(W + 18874368);   //  5,734,400
  unsigned short* geF  = (unsigned short*)(W + 24608768);   //  9,175,040
  unsigned short* aggF = (unsigned short*)(W + 33783808);   //  5,734,400
  unsigned short* WcF  = (unsigned short*)(W + 44490208);   //  1,638,400
  unsigned short* WpF  = (unsigned short*)(W + 46128608);   //    143,360
  unsigned short* WoF  = (unsigned short*)(W + 46271968);   //    229,376
  unsigned short* WgF  = (unsigned short*)(W + 46501344);   //    143,360 (end 46,644,704)
  float*          avg  = (float*)(W + 0);  // fp32 [NL][300], aliases pjF+cF (dead before k_cpj)

  hipMemsetAsync(geF, 0, 9175040, stream);   // zero-pad labels>=NL, feats>=500
  k_wprep<<<(819200 + 71680 + 114688 + 71680 + 255) / 256, 256, 0, stream>>>(
      Wc, Wp, Wo, Wg, WcF, WpF, WoF, WgF);
  k_avg<<<(NLP_ * 80 + 255) / 256, 256, 0, stream>>>(we, lidx, lmask, avg, avgb, geF);
  k_agg<<<NL_, 256, 0, stream>>>(adj, avg, nnb, aggF);
  k_gh2<<<140, 256, 0, stream>>>(aggF, WgF, bg, geF);
  k_cpj<<<dim3(32, B_), 256, 0, stream>>>(x, mask, we, WcF, bc, WpF, bp, cF, pjF);
  k_attn<<<140 * 8, 256, 0, stream>>>(pjF, cF, avgb, WoF, geF, bo, out);
  k_loss<<<1, 1024, 0, stream>>>(out, y, out + B_ * NL_);
}

// Round 8
// 992.634 us; speedup vs baseline: 1.0417x; 1.0417x over previous
//
#include <hip/hip_runtime.h>
#include <math.h>

#define B_    8
#define L_    2000
#define V_    50000
#define E_    300
#define NL_   8922
#define NLP_  8960   // padded label count (multiple of 64)
#define LW_   10
#define F_    200
#define KW_   10
#define H_    200
#define FEAT_ 500
#define LP_   1991   // L - K + 1

typedef __attribute__((ext_vector_type(8))) short bf16x8;
typedef __attribute__((ext_vector_type(4))) float f32x4;

static __device__ __forceinline__ unsigned short f2b(float f) {
  unsigned u = __builtin_bit_cast(unsigned, f);
  u += 0x7FFF + ((u >> 16) & 1);   // round-to-nearest-even
  return (unsigned short)(u >> 16);
}
static __device__ __forceinline__ unsigned short f2b_t(float f) {  // truncate (cheap)
  return (unsigned short)(__builtin_bit_cast(unsigned, f) >> 16);
}
static __device__ __forceinline__ float b2f(unsigned short u) {
  unsigned v = ((unsigned)u) << 16;
  return __builtin_bit_cast(float, v);
}
static __device__ __forceinline__ float fast_tanh(float x) {
  x = fminf(fmaxf(x, -10.f), 10.f);
  float t = __expf(2.f * x);
  return (t - 1.f) / (t + 1.f);
}
// async global->LDS DMA, 16B/lane, zero result VGPRs. LDS dst = wave-uniform base.
static __device__ __forceinline__ void stage16(const void* g, void* l) {
  __builtin_amdgcn_global_load_lds(
      (const __attribute__((address_space(1))) unsigned int*)g,
      (__attribute__((address_space(3))) unsigned int*)l, 16, 0, 0);
}

#define MFMA(a, b, c) __builtin_amdgcn_mfma_f32_16x16x32_bf16(a, b, c, 0, 0, 0)

// Fragment conventions (mfma_f32_16x16x32_bf16, m89/m91-verified):
//   A[m][k]: m = lane&15, k = (lane>>4)*8 + j
//   B[n][k]: n = lane&15, k = (lane>>4)*8 + j
//   D[m][n]: m-row = (lane>>4)*4 + reg, n-col = lane&15
// Frag-major: tile*512 shorts + lane*8 + j -> 1 KB contiguous per frag.

// ---------------------------------------------------------------------------
// avg fp32 [n][300] (k_agg input), avgb bf16 [n][320], geF feats 0..299
__global__ __launch_bounds__(256) void k_avg(const float* __restrict__ we,
                                             const int* __restrict__ lidx,
                                             const float* __restrict__ lmask,
                                             float* __restrict__ avg,
                                             unsigned short* __restrict__ avgb,
                                             unsigned short* __restrict__ geF) {
  int idx = blockIdx.x * 256 + threadIdx.x;
  if (idx >= NLP_ * 80) return;
  int n = idx / 80, e4 = idx - n * 80;
  if (n >= NL_ || e4 >= 75) {
    *(ushort4*)&avgb[(size_t)n * 320 + e4 * 4] = make_ushort4(0, 0, 0, 0);
    return;
  }
  float ax = 0.f, ay = 0.f, az = 0.f, aw = 0.f, ms = 0.f;
#pragma unroll
  for (int w = 0; w < LW_; ++w) {
    float mw = lmask[n * LW_ + w];
    const float4 f = *(const float4*)&we[(size_t)lidx[n * LW_ + w] * E_ + e4 * 4];
    ax = fmaf(f.x, mw, ax); ay = fmaf(f.y, mw, ay);
    az = fmaf(f.z, mw, az); aw = fmaf(f.w, mw, aw);
    ms += mw;
  }
  float inv = 1.f / ms;
  float4 v = {ax * inv, ay * inv, az * inv, aw * inv};
  *(float4*)&avg[(size_t)n * 300 + e4 * 4] = v;
  *(ushort4*)&avgb[(size_t)n * 320 + e4 * 4] =
      make_ushort4(f2b(v.x), f2b(v.y), f2b(v.z), f2b(v.w));
  int ntg = n >> 4, quad = (n >> 2) & 3, r = n & 3;
  int ftg = (e4 * 4) >> 4, c0 = (e4 * 4) & 15;
  size_t tb = (((size_t)ntg * 32 + ftg) << 8);
  float vv[4] = {v.x, v.y, v.z, v.w};
#pragma unroll
  for (int t = 0; t < 4; ++t)
    geF[(tb + quad * 16 + c0 + t) * 4 + r] = f2b(vv[t]);
}

// ---------------------------------------------------------------------------
// agg[n] sparse scan (float2 reads) -> aggF bf16 A-frag-major [mtile][ks(10)][512]
__global__ __launch_bounds__(256) void k_agg(const float* __restrict__ adj,
                                             const float* __restrict__ avg,
                                             const float* __restrict__ nnb,
                                             unsigned short* __restrict__ aggF) {
  __shared__ int s_idx[1024];
  __shared__ float s_val[1024];
  __shared__ float s_agg[320];
  __shared__ int s_cnt;
  const int n = blockIdx.x;
  const int tid = threadIdx.x;
  if (tid == 0) s_cnt = 0;
  __syncthreads();
  const float2* row2 = (const float2*)(adj + (size_t)n * NL_);  // NL_ even, 8B-aligned
  for (int j = tid; j < NL_ / 2; j += 256) {
    float2 v = row2[j];
    if (v.x != 0.f) {
      int p = atomicAdd(&s_cnt, 1);
      if (p < 1024) { s_idx[p] = 2 * j; s_val[p] = v.x; }
    }
    if (v.y != 0.f) {
      int p = atomicAdd(&s_cnt, 1);
      if (p < 1024) { s_idx[p] = 2 * j + 1; s_val[p] = v.y; }
    }
  }
  __syncthreads();
  const int m = min(s_cnt, 1024);
  const float inv = 1.f / nnb[n];
  float a0 = 0.f, a1 = 0.f;
  for (int i = 0; i < m; ++i) {
    const float* ar = avg + (size_t)s_idx[i] * 300;
    float v = s_val[i];
    a0 = fmaf(v, ar[tid], a0);
    if (tid < E_ - 256) a1 = fmaf(v, ar[tid + 256], a1);
  }
  s_agg[tid] = a0 * inv;
  if (tid < E_ - 256) s_agg[tid + 256] = a1 * inv;
  if (tid >= 44 && tid < 64) s_agg[tid + 256] = 0.f;  // zero e 300..319
  __syncthreads();
  if (tid < 320) {
    int e = tid;
    int ks = e >> 5, qA = (e >> 3) & 3, jj = e & 7;
    aggF[(((size_t)((n >> 4) * 10 + ks)) << 9) + ((qA << 4) + (n & 15)) * 8 + jj] =
        f2b(s_agg[e]);
  }
}

// ---------------------------------------------------------------------------
// gh via MFMA: geF[n][300..499] = relu(aggF @ WgF + bg). 140 blocks x 64 labels.
__global__ __launch_bounds__(256) void k_gh2(const unsigned short* __restrict__ aggF,
                                             const unsigned short* __restrict__ WgF,
                                             const float* __restrict__ bg,
                                             unsigned short* __restrict__ geF) {
  const int n0g = blockIdx.x * 64;
  const int tid = threadIdx.x;
  const int wv = tid >> 6, lane = tid & 63, quad = lane >> 4, c16 = lane & 15;
  const int mt = wv;
  f32x4 acc[14];
#pragma unroll
  for (int nt = 0; nt < 14; ++nt) acc[nt] = (f32x4){0.f, 0.f, 0.f, 0.f};
#pragma unroll
  for (int ks = 0; ks < 10; ++ks) {
    bf16x8 a = *(const bf16x8*)
        &aggF[(((size_t)(((n0g >> 4) + mt) * 10 + ks)) << 9) + (lane << 3)];
#pragma unroll
    for (int nt = 0; nt < 14; ++nt) {
      bf16x8 bw = *(const bf16x8*)&WgF[(((size_t)(nt * 10 + ks)) << 9) + (lane << 3)];
      acc[nt] = MFMA(a, bw, acc[nt]);
    }
  }
#pragma unroll
  for (int nt = 0; nt < 14; ++nt) {
    int h = nt * 16 + c16;
    if (h < H_) {
      float bgv = bg[h];
      int feat = 300 + h;
      int ftg = feat >> 4, cg = feat & 15;
#pragma unroll
      for (int r = 0; r < 4; ++r) {
        int n = n0g + mt * 16 + quad * 4 + r;
        if (n < NL_)
          geF[((((size_t)(n >> 4) * 32 + ftg) << 8) + (quad << 4) + cg) * 4 + r] =
              f2b(fmaxf(acc[nt][r] + bgv, 0.f));
      }
    }
  }
}

// ---------------------------------------------------------------------------
// Fused weight-layout prep: WcF, WpF, WoF, WgF (frag-major, zero-padded)
__global__ __launch_bounds__(256) void k_wprep(const float* __restrict__ Wc,
                                               const float* __restrict__ Wp,
                                               const float* __restrict__ Wo,
                                               const float* __restrict__ Wg,
                                               unsigned short* __restrict__ WcF,
                                               unsigned short* __restrict__ WpF,
                                               unsigned short* __restrict__ WoF,
                                               unsigned short* __restrict__ WgF) {
  int idx = blockIdx.x * 256 + threadIdx.x;
  if (idx < 819200) {  // WcF [koff(10)][ft(16)][ks(10)][512]
    int koff = idx / (16 * 10 * 512);
    int rem = idx - koff * (16 * 10 * 512);
    int ft = rem / (10 * 512);
    int rem2 = rem - ft * (10 * 512);
    int ks = rem2 >> 9, t = rem2 & 511;
    int lane = t >> 3, j = t & 7;
    int f = ft * 16 + (lane & 15);
    int e = ks * 32 + (lane >> 4) * 8 + j;
    float v = (f < F_ && e < E_) ? Wc[((size_t)f * E_ + e) * KW_ + koff] : 0.f;
    WcF[idx] = f2b(v);
    return;
  }
  idx -= 819200;
  if (idx < 71680) {   // WpF [et(20)][kt(7)][512]
    int et = idx / (7 * 512);
    int rem = idx - et * (7 * 512);
    int kt = rem >> 9, t = rem & 511;
    int lane = t >> 3, j = t & 7;
    int e = et * 16 + (lane & 15);
    int f = kt * 32 + (lane >> 4) * 8 + j;
    float v = (e < E_ && f < F_) ? Wp[(size_t)f * E_ + e] : 0.f;
    WpF[idx] = f2b(v);
    return;
  }
  idx -= 71680;
  if (idx < 114688) {  // WoF [g(32)][kt(7)][512]
    int g = idx / (7 * 512);
    int rem = idx - g * (7 * 512);
    int kt = rem >> 9, t = rem & 511;
    int lane = t >> 3, j = t & 7;
    int feat = g * 16 + (lane & 15);
    int f = kt * 32 + (lane >> 4) * 8 + j;
    float v = (feat < FEAT_ && f < F_) ? Wo[(size_t)f * FEAT_ + feat] : 0.f;
    WoF[idx] = f2b(v);
    return;
  }
  idx -= 114688;
  if (idx < 71680) {   // WgF [nt(14)][ks(10)][512]
    int nt = idx / (10 * 512);
    int rem = idx - nt * (10 * 512);
    int ks = rem >> 9, t = rem & 511;
    int lane = t >> 3, j = t & 7;
    int h = nt * 16 + (lane & 15);
    int e = ks * 32 + (lane >> 4) * 8 + j;
    float v = (h < H_ && e < E_) ? Wg[(size_t)e * H_ + h] : 0.f;
    WgF[idx] = f2b(v);
  }
}

// ---------------------------------------------------------------------------
// Fused conv + pj -> cF [b][ft2(16)][su(64)][512], pjF [b][lt(128)][ks(10)][512]
__global__ __launch_bounds__(256) void k_cpj(const int* __restrict__ x,
                                             const float* __restrict__ mask,
                                             const float* __restrict__ we,
                                             const unsigned short* __restrict__ WcF,
                                             const float* __restrict__ bc,
                                             const unsigned short* __restrict__ WpF,
                                             const float* __restrict__ bp,
                                             unsigned short* __restrict__ cF,
                                             unsigned short* __restrict__ pjF) {
  __shared__ __attribute__((aligned(16))) unsigned char smem[78896];
  unsigned short* s_xe  = (unsigned short*)smem;            // [73][344]
  unsigned short* s_pjF = (unsigned short*)smem;            // alias
  unsigned short* s_cA  = (unsigned short*)(smem + 50224);  // [4][7][512]

  const int b = blockIdx.y;
  const int l0 = blockIdx.x * 64;
  const int tid = threadIdx.x;
  const int wv = tid >> 6, lane = tid & 63, quad = lane >> 4, c16 = lane & 15;

  for (int i = tid; i < 73 * 75; i += 256) {
    int row = i / 75, e4 = i - row * 75;
    int l = l0 + row;
    float4 v = {0.f, 0.f, 0.f, 0.f};
    if (l < L_) {
      int bl = b * L_ + l;
      v = *(const float4*)&we[(size_t)x[bl] * E_ + e4 * 4];
      float mm = mask[bl];
      v.x *= mm; v.y *= mm; v.z *= mm; v.w *= mm;
    }
    *(ushort4*)&s_xe[row * 344 + e4 * 4] =
        make_ushort4(f2b(v.x), f2b(v.y), f2b(v.z), f2b(v.w));
  }
  for (int i = tid; i < 73 * 5; i += 256) {
    int row = i / 5, c = i - row * 5;
    *(ushort4*)&s_xe[row * 344 + (75 + c) * 4] = make_ushort4(0, 0, 0, 0);
  }
  __syncthreads();

  f32x4 acc[4][4];
#pragma unroll
  for (int mt = 0; mt < 4; ++mt)
#pragma unroll
    for (int j = 0; j < 4; ++j) acc[mt][j] = (f32x4){0.f, 0.f, 0.f, 0.f};
  for (int koff = 0; koff < KW_; ++koff) {
#pragma unroll
    for (int ks = 0; ks < 10; ++ks) {
      bf16x8 a[4];
#pragma unroll
      for (int mt = 0; mt < 4; ++mt)
        a[mt] = *(const bf16x8*)&s_xe[(mt * 16 + c16 + koff) * 344 + ks * 32 + quad * 8];
#pragma unroll
      for (int jj = 0; jj < 4; ++jj) {
        bf16x8 bw = *(const bf16x8*)
            &WcF[(((size_t)((koff * 16 + wv * 4 + jj) * 10 + ks)) << 9) + (lane << 3)];
#pragma unroll
        for (int mt = 0; mt < 4; ++mt) acc[mt][jj] = MFMA(a[mt], bw, acc[mt][jj]);
      }
    }
  }
  unsigned short* cFb = cF + (size_t)b * (16 * 64 * 512);
#pragma unroll
  for (int jj = 0; jj < 4; ++jj) {
    const int ft2 = wv * 4 + jj;
    const int f = ft2 * 16 + c16;
    const float bcv = (f < F_) ? bc[f] : 0.f;
    const int kt = ft2 >> 1;
    const int qA = ((ft2 & 1) << 1) | (c16 >> 3);
    const int jA = c16 & 7;
#pragma unroll
    for (int mt = 0; mt < 4; ++mt) {
      unsigned short u[4];
#pragma unroll
      for (int r = 0; r < 4; ++r) u[r] = f2b(fmaxf(acc[mt][jj][r] + bcv, 0.f));
      int su = (l0 >> 5) + (mt >> 1);
      int lane_c = ((((mt & 1) << 1) | (quad >> 1)) << 4) + c16;
      *(ushort4*)&cFb[(((size_t)(ft2 * 64 + su)) << 9) + lane_c * 8 + ((quad & 1) << 2)] =
          make_ushort4(u[0], u[1], u[2], u[3]);
      if (ft2 < 14) {
#pragma unroll
        for (int r = 0; r < 4; ++r)
          s_cA[(((size_t)(mt * 7 + kt)) << 9) + ((qA << 4) + quad * 4 + r) * 8 + jA] = u[r];
      }
    }
  }
  __syncthreads();

  f32x4 pacc[4][5];
#pragma unroll
  for (int mt = 0; mt < 4; ++mt)
#pragma unroll
    for (int j = 0; j < 5; ++j) pacc[mt][j] = (f32x4){0.f, 0.f, 0.f, 0.f};
#pragma unroll
  for (int kt = 0; kt < 7; ++kt) {
    bf16x8 a[4];
#pragma unroll
    for (int mt = 0; mt < 4; ++mt)
      a[mt] = *(const bf16x8*)&s_cA[(((size_t)(mt * 7 + kt)) << 9) + (lane << 3)];
#pragma unroll
    for (int j = 0; j < 5; ++j) {
      bf16x8 bw = *(const bf16x8*)
          &WpF[(((size_t)((wv * 5 + j) * 7 + kt)) << 9) + (lane << 3)];
#pragma unroll
      for (int mt = 0; mt < 4; ++mt) pacc[mt][j] = MFMA(a[mt], bw, pacc[mt][j]);
    }
  }
  __syncthreads();
#pragma unroll
  for (int j = 0; j < 5; ++j) {
    const int et = wv * 5 + j;
    const int e = et * 16 + c16;
    const float bpe = (e < E_) ? bp[e] : 0.f;
    const int ks = et >> 1;
    const int qP = ((et & 1) << 1) | (c16 >> 3);
    const int jP = c16 & 7;
#pragma unroll
    for (int mt = 0; mt < 4; ++mt) {
#pragma unroll
      for (int r = 0; r < 4; ++r) {
        float v = (e < E_) ? fast_tanh(pacc[mt][j][r] + bpe) : 0.f;
        s_pjF[(((size_t)(mt * 10 + ks)) << 9) + ((qP << 4) + quad * 4 + r) * 8 + jP] = f2b(v);
      }
    }
  }
  __syncthreads();
  {
    unsigned short* dst = pjF + (((size_t)((b * 128 + (l0 >> 4)) * 10)) << 9);
    for (int i = tid; i < 2560; i += 256)
      *(uint4*)&dst[i * 8] = *(const uint4*)&s_pjF[i * 8];
  }
}

// ---------------------------------------------------------------------------
// Fused attention + proj + logits. 64 labels/block, wave = (l-half, label-half).
// Software-pipelined: PV lags scores by one chunk -> 34 independent MFMAs per
// wave in a single no-barrier region; ONE barrier per chunk; Ps double-buffered.
__global__ __launch_bounds__(256, 2) void k_attn(
    const unsigned short* __restrict__ pjF,   // [8][128][10][512]
    const unsigned short* __restrict__ cF,    // [8][16][64][512]
    const unsigned short* __restrict__ avgb,  // [8960][320]
    const unsigned short* __restrict__ WoF,   // [32][7][512]
    const unsigned short* __restrict__ geF,   // [560][32][64][4]
    const float* __restrict__ bo,
    float* __restrict__ out) {
  __shared__ __attribute__((aligned(16))) unsigned char smem[78848];
  // pjbuf 2x20480 @0, cFbuf 2x14336 @40960, Ps 2x4096 @69632,
  // s_wsum @77824, s_sum @78336, s_lg @78592. AO aliases pjbuf (28672 B).
  unsigned short* Ps  = (unsigned short*)(smem + 69632);
  float* s_wsum = (float*)(smem + 77824);
  float* s_sum  = (float*)(smem + 78336);
  float* s_lg   = (float*)(smem + 78592);
  unsigned short* AOs = (unsigned short*)smem;

  const int tid = threadIdx.x;
  const int b  = blockIdx.x & 7;               // XCD-locality swizzle
  const int n0 = (blockIdx.x >> 3) << 6;
  const int wv = tid >> 6, lane = tid & 63, quad = lane >> 4, c16 = lane & 15;
  const int lh = wv & 1, nh = wv >> 1;

  if (tid < 64) s_lg[tid] = 0.f;

  // 32 labels' avg B-frags in regs (80 VGPRs)
  bf16x8 bavg[10][2];
#pragma unroll
  for (int ks = 0; ks < 10; ++ks)
#pragma unroll
    for (int nt = 0; nt < 2; ++nt)
      bavg[ks][nt] = *(const bf16x8*)
          &avgb[(size_t)(n0 + nh * 32 + nt * 16 + c16) * 320 + ks * 32 + quad * 8];

  const unsigned short* pjb = pjF + (size_t)b * (128 * 10 * 512);
  const unsigned short* cFb = cF + (size_t)b * (16 * 64 * 512);

  // prologue: stage pj(0) into pjbuf0
  {
    const unsigned char* pg = (const unsigned char*)pjb;
#pragma unroll
    for (int t = 0; t < 5; ++t) {
      int off = (wv * 5 + t) << 10;
      stage16(pg + off + lane * 16, smem + off);
    }
  }

  f32x4 o[2][7];
#pragma unroll
  for (int nt = 0; nt < 2; ++nt)
#pragma unroll
    for (int j = 0; j < 7; ++j) o[nt][j] = (f32x4){0.f, 0.f, 0.f, 0.f};
  float ssum[2] = {0.f, 0.f};

  for (int c = 0; c < 64; ++c) {
    __builtin_amdgcn_s_waitcnt(0);   // pj(c) and cF(c-1) staged
    __syncthreads();                 // ...visible to all waves; Ps(c-1) visible
    const int cb = c & 1;
    const unsigned short* pjcur = (const unsigned short*)(smem + cb * 20480);
    const unsigned short* cfprev = (const unsigned short*)(smem + 40960 + (cb ^ 1) * 14336);
    // stage pj(c+1) -> pjbuf[cb^1], cF(c) -> cFbuf[cb]
    if (c + 1 < 64) {
      const unsigned char* pg =
          (const unsigned char*)pjb + (((size_t)((c + 1) * 20)) << 10);
#pragma unroll
      for (int t = 0; t < 5; ++t) {
        int off = (wv * 5 + t) << 10;
        stage16(pg + off + lane * 16, smem + (cb ^ 1) * 20480 + off);
      }
    }
#pragma unroll
    for (int t = 0; t < 4; ++t) {
      int ft = wv + t * 4;
      if (ft < 14)
        stage16((const unsigned char*)cFb + (((size_t)(ft * 64 + c)) << 10) + lane * 16,
                smem + 40960 + cb * 14336 + (ft << 10));
    }
    // ---- fused MFMA region: scores(c) + PV(c-1), no internal barrier ----
    f32x4 acc0 = (f32x4){0.f, 0.f, 0.f, 0.f};
    f32x4 acc1 = (f32x4){0.f, 0.f, 0.f, 0.f};
#pragma unroll
    for (int ks = 0; ks < 10; ++ks) {
      bf16x8 a = *(const bf16x8*)(pjcur + ((lh * 10 + ks) << 9) + (lane << 3));
      acc0 = MFMA(a, bavg[ks][0], acc0);
      acc1 = MFMA(a, bavg[ks][1], acc1);
    }
    if (c) {
      const unsigned short* Pp = Ps + ((cb ^ 1) << 11);
      bf16x8 aP0 = *(const bf16x8*)(Pp + ((nh * 2) << 9) + (lane << 3));
      bf16x8 aP1 = *(const bf16x8*)(Pp + ((nh * 2 + 1) << 9) + (lane << 3));
#pragma unroll
      for (int ft = 0; ft < 7; ++ft) {
        bf16x8 bC = *(const bf16x8*)(cfprev + ((lh * 7 + ft) << 9) + (lane << 3));
        o[0][ft] = MFMA(aP0, bC, o[0][ft]);
        o[1][ft] = MFMA(aP1, bC, o[1][ft]);
      }
    }
    // ---- exp (bounded; no max) -> Ps[cb] (trunc-bf16), reg sums ----
    {
      unsigned short* Pc = Ps + (cb << 11);
      const int lb = (c << 5) + lh * 16 + quad * 4;
#pragma unroll
      for (int nt = 0; nt < 2; ++nt) {
        f32x4 av = nt ? acc1 : acc0;
        float psum = 0.f;
        unsigned short u[4];
#pragma unroll
        for (int r = 0; r < 4; ++r) {
          float p = __expf(av[r]);
          if (c >= 62 && (lb + r >= LP_)) p = 0.f;
          u[r] = f2b_t(p);
          psum += b2f(u[r]);   // sum the stored values -> exact normalization
        }
        *(ushort4*)&Pc[((nh * 2 + nt) << 9) +
                       ((lh * 2 + (quad >> 1)) * 16 + c16) * 8 + ((quad & 1) << 2)] =
            make_ushort4(u[0], u[1], u[2], u[3]);
        psum += __shfl_xor(psum, 16);
        psum += __shfl_xor(psum, 32);
        ssum[nt] += psum;
      }
    }
  }
  // ---- final PV(63) ----
  __builtin_amdgcn_s_waitcnt(0);
  __syncthreads();
  {
    const unsigned short* cfprev = (const unsigned short*)(smem + 40960 + 14336);
    const unsigned short* Pp = Ps + (1 << 11);
    bf16x8 aP0 = *(const bf16x8*)(Pp + ((nh * 2) << 9) + (lane << 3));
    bf16x8 aP1 = *(const bf16x8*)(Pp + ((nh * 2 + 1) << 9) + (lane << 3));
#pragma unroll
    for (int ft = 0; ft < 7; ++ft) {
      bf16x8 bC = *(const bf16x8*)(cfprev + ((lh * 7 + ft) << 9) + (lane << 3));
      o[0][ft] = MFMA(aP0, bC, o[0][ft]);
      o[1][ft] = MFMA(aP1, bC, o[1][ft]);
    }
  }

  // ---- combine sums across l-half wave pairs ----
  if (lane < 16) {
    s_wsum[wv * 32 + lane] = ssum[0];
    s_wsum[wv * 32 + 16 + lane] = ssum[1];
  }
  __syncthreads();
  if (tid < 64) {
    int g = tid >> 5, idx = tid & 31;
    s_sum[tid] = s_wsum[(g * 2) * 32 + idx] + s_wsum[(g * 2 + 1) * 32 + idx];
  }
  __syncthreads();
  // ---- normalize -> AO (A-frag-major [ntile(4)][kt(7)][512], aliases pjbuf) ----
#pragma unroll
  for (int nt = 0; nt < 2; ++nt) {
    const int ntile = nh * 2 + nt;
    float inv4[4];
#pragma unroll
    for (int r = 0; r < 4; ++r) inv4[r] = 1.f / s_sum[ntile * 16 + quad * 4 + r];
#pragma unroll
    for (int ft = 0; ft < 7; ++ft) {
      int f = (lh * 7 + ft) * 16 + c16;
      int kt = f >> 5, qA = (f >> 3) & 3, jA = f & 7;
#pragma unroll
      for (int r = 0; r < 4; ++r)
        AOs[((ntile * 7 + kt) << 9) + ((qA << 4) + quad * 4 + r) * 8 + jA] =
            f2b(o[nt][ft][r] * inv4[r]);
    }
  }
  __syncthreads();
  // ---- proj: waves split feat (8 tiles each); relu + dot geF -> logits ----
  float la[4][4];
#pragma unroll
  for (int nt = 0; nt < 4; ++nt)
#pragma unroll
    for (int r = 0; r < 4; ++r) la[nt][r] = 0.f;
#pragma unroll
  for (int i = 0; i < 8; ++i) {
    const int ftg = wv * 8 + i;
    const int feat = (ftg << 4) + c16;
    f32x4 pa[4];
#pragma unroll
    for (int nt = 0; nt < 4; ++nt) pa[nt] = (f32x4){0.f, 0.f, 0.f, 0.f};
    const unsigned short* wof = WoF + (((size_t)(ftg * 7)) << 9) + (lane << 3);
#pragma unroll
    for (int kt = 0; kt < 7; ++kt) {
      bf16x8 bw = *(const bf16x8*)(wof + (kt << 9));
#pragma unroll
      for (int nt = 0; nt < 4; ++nt) {
        bf16x8 aa = *(const bf16x8*)&AOs[((nt * 7 + kt) << 9) + (lane << 3)];
        pa[nt] = MFMA(aa, bw, pa[nt]);
      }
    }
    const float bof = (feat < FEAT_) ? bo[feat] : 0.f;
#pragma unroll
    for (int nt = 0; nt < 4; ++nt) {
      ushort4 g4 = *(const ushort4*)
          &geF[((((size_t)(n0 >> 4) + nt) * 32 + ftg) << 8) + (lane << 2)];
      float gv[4] = {b2f(g4.x), b2f(g4.y), b2f(g4.z), b2f(g4.w)};
#pragma unroll
      for (int r = 0; r < 4; ++r) {
        float pv = fmaxf(pa[nt][r] + bof, 0.f);
        la[nt][r] = fmaf(pv, gv[r], la[nt][r]);
      }
    }
  }
#pragma unroll
  for (int nt = 0; nt < 4; ++nt)
#pragma unroll
    for (int r = 0; r < 4; ++r) {
      float v = la[nt][r];
      v += __shfl_xor(v, 1); v += __shfl_xor(v, 2);
      v += __shfl_xor(v, 4); v += __shfl_xor(v, 8);
      if (c16 == 0) atomicAdd(&s_lg[nt * 16 + quad * 4 + r], v);
    }
  __syncthreads();
  if (tid < 64) {
    int ng = n0 + tid;
    if (ng < NL_) out[(size_t)b * NL_ + ng] = s_lg[tid];
  }
}

// ---------------------------------------------------------------------------
__global__ __launch_bounds__(1024) void k_loss(const float* __restrict__ lgts,
                                               const float* __restrict__ y,
                                               float* __restrict__ loss) {
  __shared__ float red[1024];
  const int tid = threadIdx.x;
  float s = 0.f;
  for (int i = tid; i < B_ * NL_; i += 1024) {
    float l = lgts[i], yy = y[i];
    s += fmaxf(l, 0.f) - l * yy + log1pf(expf(-fabsf(l)));
  }
  red[tid] = s;
  __syncthreads();
  for (int st = 512; st > 0; st >>= 1) {
    if (tid < st) red[tid] += red[tid + st];
    __syncthreads();
  }
  if (tid == 0) loss[0] = red[0] * (1.f / B_);
}

// ---------------------------------------------------------------------------
extern "C" void kernel_launch(void* const* d_in, const int* in_sizes, int n_in,
                              void* d_out, int out_size, void* d_ws, size_t ws_size,
                              hipStream_t stream) {
  const int*   x     = (const int*)  d_in[0];
  const float* y     = (const float*)d_in[1];
  const float* mask  = (const float*)d_in[2];
  const float* we    = (const float*)d_in[3];
  const int*   lidx  = (const int*)  d_in[4];
  const float* lmask = (const float*)d_in[5];
  const float* adj   = (const float*)d_in[6];
  const float* nnb   = (const float*)d_in[7];
  const float* Wg    = (const float*)d_in[8];
  const float* bg    = (const float*)d_in[9];
  const float* Wc    = (const float*)d_in[10];
  const float* bc    = (const float*)d_in[11];
  const float* Wp    = (const float*)d_in[12];
  const float* bp    = (const float*)d_in[13];
  const float* Wo    = (const float*)d_in[14];
  const float* bo    = (const float*)d_in[15];
  float* out = (float*)d_out;
  char* W = (char*)d_ws;

  unsigned short* pjF  = (unsigned short*)(W + 0);          // 10,485,760
  unsigned short* cF   = (unsigned short*)(W + 10485760);   //  8,388,608
  unsigned short* avgb = (unsigned short*)(W + 18874368);   //  5,734,400
  unsigned short* geF  = (unsigned short*)(W + 24608768);   //  9,175,040
  unsigned short* aggF = (unsigned short*)(W + 33783808);   //  5,734,400
  unsigned short* WcF  = (unsigned short*)(W + 44490208);   //  1,638,400
  unsigned short* WpF  = (unsigned short*)(W + 46128608);   //    143,360
  unsigned short* WoF  = (unsigned short*)(W + 46271968);   //    229,376
  unsigned short* WgF  = (unsigned short*)(W + 46501344);   //    143,360 (end 46,644,704)
  float*          avg  = (float*)(W + 0);  // fp32 [NL][300], aliases pjF+cF (dead before k_cpj)

  hipMemsetAsync(geF, 0, 9175040, stream);   // zero-pad labels>=NL, feats>=500
  k_wprep<<<(819200 + 71680 + 114688 + 71680 + 255) / 256, 256, 0, stream>>>(
      Wc, Wp, Wo, Wg, WcF, WpF, WoF, WgF);
  k_avg<<<(NLP_ * 80 + 255) / 256, 256, 0, stream>>>(we, lidx, lmask, avg, avgb, geF);
  k_agg<<<NL_, 256, 0, stream>>>(adj, avg, nnb, aggF);
  k_gh2<<<140, 256, 0, stream>>>(aggF, WgF, bg, geF);
  k_cpj<<<dim3(32, B_), 256, 0, stream>>>(x, mask, we, WcF, bc, WpF, bp, cF, pjF);
  k_attn<<<140 * 8, 256, 0, stream>>>(pjF, cF, avgb, WoF, geF, bo, out);
  k_loss<<<1, 1024, 0, stream>>>(out, y, out + B_ * NL_);
}